// Round 18
// baseline (197.768 us; speedup 1.0000x reference)
//
#include <hip/hip_runtime.h>
#include <hip/hip_fp16.h>
#include <math.h>

#define H_DIM 180
#define W_DIM 360
#define CH    256
#define NHEAD 8
#define HD    32
#define MPIX  (H_DIM * W_DIM)   // 64800
#define KDIM  256

typedef _Float16 f16x8 __attribute__((ext_vector_type(8)));
typedef _Float16 h2    __attribute__((ext_vector_type(2)));
typedef float    f32x4 __attribute__((ext_vector_type(4)));

#if __has_builtin(__builtin_amdgcn_fdot2)
#define HAS_FDOT2 1
#else
#define HAS_FDOT2 0
#endif

__device__ __forceinline__ h2 pack2(float a, float b) {
#if __has_builtin(__builtin_amdgcn_cvt_pkrtz)
    return __builtin_bit_cast(h2, __builtin_amdgcn_cvt_pkrtz(a, b));
#else
    h2 r; r.x = (_Float16)a; r.y = (_Float16)b; return r;
#endif
}

// ---------------------------------------------------------------------------
// Kernel 0: fp32 -> fp16 conversions. y=0: X; y=1: w_qkv -> Wqt[768][256]
// (transposed); y=2: w_proj -> Wpt[256][256] (transposed).
// ---------------------------------------------------------------------------
__global__ __launch_bounds__(256)
void convert_kernel(const float* __restrict__ X, const float* __restrict__ Wq,
                    const float* __restrict__ Wp, _Float16* __restrict__ Xh,
                    _Float16* __restrict__ Wqt, _Float16* __restrict__ Wpt)
{
    const int tid = blockIdx.x * 256 + threadIdx.x;
    if (blockIdx.y == 0) {
        const float4* X4 = reinterpret_cast<const float4*>(X);
        const float4 a = X4[tid * 2];
        const float4 b = X4[tid * 2 + 1];
        uint4 o;
        o.x = __builtin_bit_cast(unsigned, pack2(a.x, a.y));
        o.y = __builtin_bit_cast(unsigned, pack2(a.z, a.w));
        o.z = __builtin_bit_cast(unsigned, pack2(b.x, b.y));
        o.w = __builtin_bit_cast(unsigned, pack2(b.z, b.w));
        reinterpret_cast<uint4*>(Xh)[tid] = o;
    } else if (blockIdx.y == 1) {
        if (tid < 768 * 256) {
            const int n = tid >> 8, k = tid & 255;
            Wqt[tid] = (_Float16)Wq[k * 768 + n];
        }
    } else {
        if (tid < 256 * 256) {
            const int n = tid >> 8, k = tid & 255;
            Wpt[tid] = (_Float16)Wp[k * 256 + n];
        }
    }
}

// ---------------------------------------------------------------------------
// MFMA fp16 GEMM, 128x128 tile, 4 waves (64x64 each), BK=64, K=256.
// r16 sync structure (2x __syncthreads per K-tile, global_load_lds staging)
// + T2 XOR bank swizzle (m201 recipe): LDS holds A[row][unit ^ (row&7)].
//   - staging: LDS dest stays LINEAR (DMA constraint); the per-lane GLOBAL
//     source unit is pre-swizzled: lane (srow,sunit) loads unit sunit^srow.
//     Rows stay 128B-contiguous per chunk -> coalescing unchanged.
//   - fragment read applies the same XOR: unit (kk/8 + lane>>4) ^ (lane&7).
//   16-way bank conflict (16 lanes @128B stride -> one 4-bank cluster)
//   becomes 2-way (free).
// MODE 0: qkv epilogue -> coalesced fp16 scatter via per-wave LDS transpose.
// MODE 1: proj epilogue (bias, fp32 out [M][NB]).
// XCD-chunked bijective swizzle (m204) kept (verified -5.5 us in r15).
// ---------------------------------------------------------------------------
template<int NB, int MODE>
__global__ __launch_bounds__(256)
void mfma_gemm_kernel(const _Float16* __restrict__ A,
                      const _Float16* __restrict__ Bt,
                      const float* __restrict__ bias,
                      _Float16* __restrict__ qo, _Float16* __restrict__ ko,
                      _Float16* __restrict__ vo, float* __restrict__ outf,
                      int M)
{
    __shared__ __align__(16) _Float16 Alds[128 * 64];
    __shared__ __align__(16) _Float16 Blds[128 * 64];

    const int tid  = threadIdx.x;
    const int wid  = tid >> 6;
    const int lane = tid & 63;

    // XCD-chunked bijective swizzle (m204): nwg not divisible by 8.
    const int nwg  = gridDim.x * gridDim.y;
    const int orig = blockIdx.x + gridDim.x * blockIdx.y;
    const int qq   = nwg >> 3;
    const int rr   = nwg & 7;
    const int xcd  = orig & 7;
    const int blk  = orig >> 3;
    const int wgid = (xcd < rr ? xcd * (qq + 1)
                               : rr * (qq + 1) + (xcd - rr) * qq) + blk;
    const int bn   = (wgid % gridDim.x) * 128;
    const int bm   = (wgid / gridDim.x) * 128;

    const int wr   = wid >> 1;
    const int wc   = wid & 1;

    f32x4 acc[4][4] = {};

    const int srow  = lane >> 3;            // 0..7 (row within 8-row chunk)
    const int sunit = lane & 7;             // 0..7 (16B unit slot in LDS row)
    const int gux   = (sunit ^ srow) * 16;  // pre-swizzled GLOBAL unit (m173)

    for (int k0 = 0; k0 < KDIM; k0 += 64) {
        #pragma unroll
        for (int i = 0; i < 4; ++i) {
            const int chunk = i * 4 + wid;
            const int row   = chunk * 8 + srow;
            int am = bm + row;
            am = (am < M) ? am : (M - 1);
            const char* asrc = (const char*)(A + (size_t)am * KDIM + k0) + gux;
            __builtin_amdgcn_global_load_lds(
                (const __attribute__((address_space(1))) void*)asrc,
                (__attribute__((address_space(3))) void*)((char*)Alds + chunk * 1024),
                16, 0, 0);
            const char* bsrc = (const char*)(Bt + (size_t)(bn + row) * KDIM + k0) + gux;
            __builtin_amdgcn_global_load_lds(
                (const __attribute__((address_space(1))) void*)bsrc,
                (__attribute__((address_space(3))) void*)((char*)Blds + chunk * 1024),
                16, 0, 0);
        }
        __syncthreads();
        #pragma unroll
        for (int kk = 0; kk < 64; kk += 32) {
            // unit U = kk/8 + (lane>>4); stored at slot U ^ (row&7), row&7 = lane&7
            const int ux = ((kk >> 3) + (lane >> 4)) ^ (lane & 7);
            f16x8 af[4], bf[4];
            #pragma unroll
            for (int t = 0; t < 4; ++t) {
                af[t] = *(const f16x8*)&Alds[(wr * 64 + t * 16 + (lane & 15)) * 64 + ux * 8];
                bf[t] = *(const f16x8*)&Blds[(wc * 64 + t * 16 + (lane & 15)) * 64 + ux * 8];
            }
            #pragma unroll
            for (int fi = 0; fi < 4; ++fi)
                #pragma unroll
                for (int fj = 0; fj < 4; ++fj)
                    acc[fi][fj] = __builtin_amdgcn_mfma_f32_16x16x32_f16(
                        af[fi], bf[fj], acc[fi][fj], 0, 0, 0);
        }
        __syncthreads();
    }

    // epilogue — C/D layout: col = lane&15, row = (lane>>4)*4 + j
    const int lc  = lane & 15;
    const int lrb = (lane >> 4) * 4;
    if (MODE == 0) {
        const float scale = 0.17677669529663687f;
        _Float16* sw = Alds + wid * 640;   // 16 rows x 34 f16 (+pad), per-wave
        const int row = lane >> 2;          // 0..15
        const int seg = lane & 3;           // 0..3
        #pragma unroll
        for (int fi = 0; fi < 4; ++fi) {
            #pragma unroll
            for (int fp = 0; fp < 2; ++fp) {       // fj pair (2fp, 2fp+1)
                #pragma unroll
                for (int ff = 0; ff < 2; ++ff) {
                    const int fj = fp * 2 + ff;
                    const int c = bn + wc * 64 + fj * 16 + lc;
                    const float bv = bias[c];
                    const float scl = ((c >> 8) == 0) ? scale : 1.0f;
                    #pragma unroll
                    for (int j = 0; j < 4; ++j)
                        sw[(lrb + j) * 34 + ff * 16 + lc] =
                            (_Float16)((acc[fi][fj][j] + bv) * scl);
                }
                const int c0 = bn + wc * 64 + fp * 32;
                const int which = c0 >> 8;          // 0=q 1=k 2=v
                const int head  = (c0 >> 5) & 7;
                _Float16* dst = (which == 0) ? qo : (which == 1) ? ko : vo;
                const int m = bm + wr * 64 + fi * 16 + row;
                f16x8 vv = *(const f16x8*)&sw[row * 34 + seg * 8];
                if (m < M)
                    *(f16x8*)&dst[((size_t)head * M + m) * HD + seg * 8] = vv;
            }
        }
    } else {
        #pragma unroll
        for (int fj = 0; fj < 4; ++fj) {
            const int c = bn + wc * 64 + fj * 16 + lc;
            const float bv = bias[c];
            #pragma unroll
            for (int fi = 0; fi < 4; ++fi) {
                #pragma unroll
                for (int j = 0; j < 4; ++j) {
                    const int m = bm + wr * 64 + fi * 16 + lrb + j;
                    if (m < M)
                        outf[(size_t)m * NB + c] = acc[fi][fj][j] + bv;
                }
            }
        }
    }
}

// ---------------------------------------------------------------------------
// Attention (round-16 verified, UNCHANGED): one query per thread,
// (head, 8h x 32w tile), single time-shared 37.5 KB buffer, K/V via
// global_load_lds DMA, t-major conflict-free layout, no max-subtraction,
// q-hoist, softmax in V-DMA shadow, 4-chain ILP, per-head XCD swizzle.
// ---------------------------------------------------------------------------
#define KROWS 14
#define KCOLS 38
#define KUNITS (KROWS * KCOLS * 4)   // 2128 x 16B
#define KUNITS_PAD 2304              // 9 x 256 (pad rows clamp-read, never used)

__device__ __forceinline__ void stage_dma(const uint4* __restrict__ src,
                                          uint4* __restrict__ dstlds,
                                          int n, int r0, int w0, int tid)
{
    const int wid  = tid >> 6;
    const int lane = tid & 63;
    #pragma unroll
    for (int it = 0; it < 9; ++it) {
        const int u0 = it * 256 + wid * 64;   // wave-uniform LDS base
        const int u  = u0 + lane;
        const int row = u / (KCOLS * 4);      // t-major: u = row*152 + t*38 + col
        const int rem = u - row * (KCOLS * 4);
        const int t   = rem / KCOLS;
        const int col = rem - t * KCOLS;
        int grow = r0 + row;
        if (grow > H_DIM - 1) grow = H_DIM - 1;
        int gcol = w0 - 3 + col;
        if (gcol < 0) gcol += W_DIM;
        else if (gcol >= W_DIM) gcol -= W_DIM;
        const size_t gidx = (((size_t)n * H_DIM + grow) * W_DIM + gcol) * 4 + t;
        __builtin_amdgcn_global_load_lds(
            (const __attribute__((address_space(1))) void*)(src + gidx),
            (__attribute__((address_space(3))) void*)(dstlds + u0), 16, 0, 0);
    }
}

__global__ __launch_bounds__(256)
void natten_attn_kernel(const _Float16* __restrict__ q,   // [8][M][32]
                        const uint4* __restrict__ kb,
                        const uint4* __restrict__ vb,
                        const float* __restrict__ rpb,    // [8][13][13]
                        _Float16* __restrict__ outh)      // [M][256]
{
    __shared__ uint4 kvs[KUNITS_PAD];
    __shared__ float rpbs[169];

    const int tid = threadIdx.x;
    const int n  = blockIdx.z;

    // per-head XCD-chunked bijective swizzle (m204): y-neighbors co-resident
    int w0, h0;
    {
        const int nwg   = gridDim.x * gridDim.y;          // 276
        const int local = blockIdx.x + gridDim.x * blockIdx.y;
        const int qq    = nwg >> 3;
        const int rr    = nwg & 7;
        const int xcd   = local & 7;
        const int blk   = local >> 3;
        const int lp    = (xcd < rr ? xcd * (qq + 1)
                                    : rr * (qq + 1) + (xcd - rr) * qq) + blk;
        w0 = (lp % gridDim.x) * 32;
        h0 = (lp / gridDim.x) * 8;
    }

    int r0 = h0 - 3;
    if (r0 < 0) r0 = 0;
    if (r0 > H_DIM - 7) r0 = H_DIM - 7;

    if (tid < 169) rpbs[tid] = rpb[n * 169 + tid];

    const int hl = tid >> 5;
    const int wl = tid & 31;
    const int h = h0 + hl;
    const int w = w0 + wl;
    const bool valid = (h < H_DIM) && (w < W_DIM);

    // ---- q global load issued BEFORE staging: completes under the DMA wait
    const int ha = (h < H_DIM) ? h : H_DIM - 1;
    const int wa = (w < W_DIM) ? w : W_DIM - 1;
    const uint4* qp = reinterpret_cast<const uint4*>(
        q + ((size_t)n * MPIX + (size_t)ha * W_DIM + wa) * HD);
    uint4 q0 = qp[0], q1 = qp[1], q2 = qp[2], q3 = qp[3];

    // ---- phase 1: stage K via DMA ----
    stage_dma(kb, kvs, n, r0, w0, tid);
    __syncthreads();

    h2 qh[16];
    qh[0]  = __builtin_bit_cast(h2, q0.x); qh[1]  = __builtin_bit_cast(h2, q0.y);
    qh[2]  = __builtin_bit_cast(h2, q0.z); qh[3]  = __builtin_bit_cast(h2, q0.w);
    qh[4]  = __builtin_bit_cast(h2, q1.x); qh[5]  = __builtin_bit_cast(h2, q1.y);
    qh[6]  = __builtin_bit_cast(h2, q1.z); qh[7]  = __builtin_bit_cast(h2, q1.w);
    qh[8]  = __builtin_bit_cast(h2, q2.x); qh[9]  = __builtin_bit_cast(h2, q2.y);
    qh[10] = __builtin_bit_cast(h2, q2.z); qh[11] = __builtin_bit_cast(h2, q2.w);
    qh[12] = __builtin_bit_cast(h2, q3.x); qh[13] = __builtin_bit_cast(h2, q3.y);
    qh[14] = __builtin_bit_cast(h2, q3.z); qh[15] = __builtin_bit_cast(h2, q3.w);

    float sc[49];
    int ri0 = 0;

    if (valid) {
        int sh = h - 3;
        if (sh < 0) sh = 0;
        if (sh > H_DIM - 7) sh = H_DIM - 7;
        ri0 = sh - r0;
        const int rh0 = sh - h + 6;

        #pragma unroll
        for (int oi = 0; oi < 7; ++oi) {
            const int rb = (ri0 + oi) * (KCOLS * 4);
            #pragma unroll
            for (int oj = 0; oj < 7; ++oj) {
                const int base = rb + wl + oj;
                float d0 = 0.f, d1 = 0.f, d2 = 0.f, d3 = 0.f;
                const uint4 ku0 = kvs[base];
                const uint4 ku1 = kvs[base + KCOLS];
                const uint4 ku2 = kvs[base + 2 * KCOLS];
                const uint4 ku3 = kvs[base + 3 * KCOLS];
#if HAS_FDOT2
                d0 = __builtin_amdgcn_fdot2(__builtin_bit_cast(h2, ku0.x), qh[0],  d0, false);
                d1 = __builtin_amdgcn_fdot2(__builtin_bit_cast(h2, ku1.x), qh[4],  d1, false);
                d2 = __builtin_amdgcn_fdot2(__builtin_bit_cast(h2, ku2.x), qh[8],  d2, false);
                d3 = __builtin_amdgcn_fdot2(__builtin_bit_cast(h2, ku3.x), qh[12], d3, false);
                d0 = __builtin_amdgcn_fdot2(__builtin_bit_cast(h2, ku0.y), qh[1],  d0, false);
                d1 = __builtin_amdgcn_fdot2(__builtin_bit_cast(h2, ku1.y), qh[5],  d1, false);
                d2 = __builtin_amdgcn_fdot2(__builtin_bit_cast(h2, ku2.y), qh[9],  d2, false);
                d3 = __builtin_amdgcn_fdot2(__builtin_bit_cast(h2, ku3.y), qh[13], d3, false);
                d0 = __builtin_amdgcn_fdot2(__builtin_bit_cast(h2, ku0.z), qh[2],  d0, false);
                d1 = __builtin_amdgcn_fdot2(__builtin_bit_cast(h2, ku1.z), qh[6],  d1, false);
                d2 = __builtin_amdgcn_fdot2(__builtin_bit_cast(h2, ku2.z), qh[10], d2, false);
                d3 = __builtin_amdgcn_fdot2(__builtin_bit_cast(h2, ku3.z), qh[14], d3, false);
                d0 = __builtin_amdgcn_fdot2(__builtin_bit_cast(h2, ku0.w), qh[3],  d0, false);
                d1 = __builtin_amdgcn_fdot2(__builtin_bit_cast(h2, ku1.w), qh[7],  d1, false);
                d2 = __builtin_amdgcn_fdot2(__builtin_bit_cast(h2, ku2.w), qh[11], d2, false);
                d3 = __builtin_amdgcn_fdot2(__builtin_bit_cast(h2, ku3.w), qh[15], d3, false);
#else
                {
                    h2 a, b;
                    a = __builtin_bit_cast(h2, ku0.x); b = qh[0];
                    d0 += (float)a.x * (float)b.x + (float)a.y * (float)b.y;
                    a = __builtin_bit_cast(h2, ku0.y); b = qh[1];
                    d0 += (float)a.x * (float)b.x + (float)a.y * (float)b.y;
                    a = __builtin_bit_cast(h2, ku0.z); b = qh[2];
                    d0 += (float)a.x * (float)b.x + (float)a.y * (float)b.y;
                    a = __builtin_bit_cast(h2, ku0.w); b = qh[3];
                    d0 += (float)a.x * (float)b.x + (float)a.y * (float)b.y;
                    a = __builtin_bit_cast(h2, ku1.x); b = qh[4];
                    d1 += (float)a.x * (float)b.x + (float)a.y * (float)b.y;
                    a = __builtin_bit_cast(h2, ku1.y); b = qh[5];
                    d1 += (float)a.x * (float)b.x + (float)a.y * (float)b.y;
                    a = __builtin_bit_cast(h2, ku1.z); b = qh[6];
                    d1 += (float)a.x * (float)b.x + (float)a.y * (float)b.y;
                    a = __builtin_bit_cast(h2, ku1.w); b = qh[7];
                    d1 += (float)a.x * (float)b.x + (float)a.y * (float)b.y;
                    a = __builtin_bit_cast(h2, ku2.x); b = qh[8];
                    d2 += (float)a.x * (float)b.x + (float)a.y * (float)b.y;
                    a = __builtin_bit_cast(h2, ku2.y); b = qh[9];
                    d2 += (float)a.x * (float)b.x + (float)a.y * (float)b.y;
                    a = __builtin_bit_cast(h2, ku2.z); b = qh[10];
                    d2 += (float)a.x * (float)b.x + (float)a.y * (float)b.y;
                    a = __builtin_bit_cast(h2, ku2.w); b = qh[11];
                    d2 += (float)a.x * (float)b.x + (float)a.y * (float)b.y;
                    a = __builtin_bit_cast(h2, ku3.x); b = qh[12];
                    d3 += (float)a.x * (float)b.x + (float)a.y * (float)b.y;
                    a = __builtin_bit_cast(h2, ku3.y); b = qh[13];
                    d3 += (float)a.x * (float)b.x + (float)a.y * (float)b.y;
                    a = __builtin_bit_cast(h2, ku3.z); b = qh[14];
                    d3 += (float)a.x * (float)b.x + (float)a.y * (float)b.y;
                    a = __builtin_bit_cast(h2, ku3.w); b = qh[15];
                    d3 += (float)a.x * (float)b.x + (float)a.y * (float)b.y;
                }
#endif
                sc[oi * 7 + oj] = ((d0 + d1) + (d2 + d3))
                                + rpbs[(rh0 + oi) * 13 + 3 + oj];
            }
        }
    }
    __syncthreads();

    // ---- phase 2: ISSUE V DMA, then do softmax in the DMA shadow ----
    stage_dma(vb, kvs, n, r0, w0, tid);

    float inv = 0.f;
    if (valid) {
        float ssum = 0.f;
        #pragma unroll
        for (int i = 0; i < 49; ++i) { sc[i] = __expf(sc[i]); ssum += sc[i]; }
        inv = 1.f / ssum;
    }
    __syncthreads();

    if (!valid) return;   // no barriers past this point

    float acc[32];
    #pragma unroll
    for (int t = 0; t < 32; ++t) acc[t] = 0.f;
    #pragma unroll
    for (int oi = 0; oi < 7; ++oi) {
        const int rb = (ri0 + oi) * (KCOLS * 4);
        #pragma unroll
        for (int oj = 0; oj < 7; ++oj) {
            const int base = rb + wl + oj;
            const float a = sc[oi * 7 + oj];
            #pragma unroll
            for (int t = 0; t < 4; ++t) {
                const uint4 vv = kvs[base + t * KCOLS];
                h2 v0 = __builtin_bit_cast(h2, vv.x);
                h2 v1 = __builtin_bit_cast(h2, vv.y);
                h2 v2 = __builtin_bit_cast(h2, vv.z);
                h2 v3 = __builtin_bit_cast(h2, vv.w);
                acc[t*8+0] += a * (float)v0.x; acc[t*8+1] += a * (float)v0.y;
                acc[t*8+2] += a * (float)v1.x; acc[t*8+3] += a * (float)v1.y;
                acc[t*8+4] += a * (float)v2.x; acc[t*8+5] += a * (float)v2.y;
                acc[t*8+6] += a * (float)v3.x; acc[t*8+7] += a * (float)v3.y;
            }
        }
    }

    uint4 o[4];
    #pragma unroll
    for (int t = 0; t < 4; ++t) {
        h2 p0 = { (_Float16)(acc[t*8+0] * inv), (_Float16)(acc[t*8+1] * inv) };
        h2 p1 = { (_Float16)(acc[t*8+2] * inv), (_Float16)(acc[t*8+3] * inv) };
        h2 p2 = { (_Float16)(acc[t*8+4] * inv), (_Float16)(acc[t*8+5] * inv) };
        h2 p3 = { (_Float16)(acc[t*8+6] * inv), (_Float16)(acc[t*8+7] * inv) };
        o[t].x = __builtin_bit_cast(unsigned, p0);
        o[t].y = __builtin_bit_cast(unsigned, p1);
        o[t].z = __builtin_bit_cast(unsigned, p2);
        o[t].w = __builtin_bit_cast(unsigned, p3);
    }
    uint4* op = reinterpret_cast<uint4*>(
        outh + (((size_t)h * W_DIM + w) * CH + n * HD));
    #pragma unroll
    for (int t = 0; t < 4; ++t) op[t] = o[t];
}

// ---------------------------------------------------------------------------
extern "C" void kernel_launch(void* const* d_in, const int* in_sizes, int n_in,
                              void* d_out, int out_size, void* d_ws, size_t ws_size,
                              hipStream_t stream)
{
    const float* x      = (const float*)d_in[0];
    const float* w_qkv  = (const float*)d_in[1];
    const float* b_qkv  = (const float*)d_in[2];
    const float* rpb    = (const float*)d_in[3];
    const float* w_proj = (const float*)d_in[4];
    const float* b_proj = (const float*)d_in[5];
    float* out = (float*)d_out;

    const int M = MPIX;
    const size_t nelem = (size_t)M * KDIM;

    _Float16* Xh  = (_Float16*)d_ws;
    _Float16* Wqt = Xh  + nelem;
    _Float16* Wpt = Wqt + 768 * 256;
    _Float16* qb  = Wpt + 256 * 256;
    _Float16* kb  = qb  + nelem;
    _Float16* vb  = kb  + nelem;
    _Float16* ah  = vb  + nelem;

    const size_t need = (5 * nelem + 768 * 256 + 256 * 256) * sizeof(_Float16);
    if (ws_size < need) return;

    dim3 blk(256);
    convert_kernel<<<dim3(8100, 3), blk, 0, stream>>>(x, w_qkv, w_proj, Xh, Wqt, Wpt);

    mfma_gemm_kernel<768, 0><<<dim3(6, 507), blk, 0, stream>>>(
        Xh, Wqt, b_qkv, qb, kb, vb, nullptr, M);

    natten_attn_kernel<<<dim3(12, 23, NHEAD), blk, 0, stream>>>(
        qb, (const uint4*)kb, (const uint4*)vb, rpb, ah);

    mfma_gemm_kernel<256, 1><<<dim3(2, 507), blk, 0, stream>>>(
        ah, Wpt, b_proj, nullptr, nullptr, nullptr, out, M);
}

// Round 19
// 190.425 us; speedup vs baseline: 1.0386x; 1.0386x over previous
//
#include <hip/hip_runtime.h>
#include <hip/hip_fp16.h>
#include <math.h>

#define H_DIM 180
#define W_DIM 360
#define CH    256
#define NHEAD 8
#define HD    32
#define MPIX  (H_DIM * W_DIM)   // 64800
#define KDIM  256

typedef _Float16 f16x8 __attribute__((ext_vector_type(8)));
typedef _Float16 h2    __attribute__((ext_vector_type(2)));
typedef float    f32x4 __attribute__((ext_vector_type(4)));

#if __has_builtin(__builtin_amdgcn_fdot2)
#define HAS_FDOT2 1
#else
#define HAS_FDOT2 0
#endif

__device__ __forceinline__ h2 pack2(float a, float b) {
#if __has_builtin(__builtin_amdgcn_cvt_pkrtz)
    return __builtin_bit_cast(h2, __builtin_amdgcn_cvt_pkrtz(a, b));
#else
    h2 r; r.x = (_Float16)a; r.y = (_Float16)b; return r;
#endif
}

// ---------------------------------------------------------------------------
// Kernel 0: fp32 -> fp16 conversions. y=0: X; y=1: w_qkv -> Wqt[768][256]
// (transposed); y=2: w_proj -> Wpt[256][256] (transposed).
// ---------------------------------------------------------------------------
__global__ __launch_bounds__(256)
void convert_kernel(const float* __restrict__ X, const float* __restrict__ Wq,
                    const float* __restrict__ Wp, _Float16* __restrict__ Xh,
                    _Float16* __restrict__ Wqt, _Float16* __restrict__ Wpt)
{
    const int tid = blockIdx.x * 256 + threadIdx.x;
    if (blockIdx.y == 0) {
        const float4* X4 = reinterpret_cast<const float4*>(X);
        const float4 a = X4[tid * 2];
        const float4 b = X4[tid * 2 + 1];
        uint4 o;
        o.x = __builtin_bit_cast(unsigned, pack2(a.x, a.y));
        o.y = __builtin_bit_cast(unsigned, pack2(a.z, a.w));
        o.z = __builtin_bit_cast(unsigned, pack2(b.x, b.y));
        o.w = __builtin_bit_cast(unsigned, pack2(b.z, b.w));
        reinterpret_cast<uint4*>(Xh)[tid] = o;
    } else if (blockIdx.y == 1) {
        if (tid < 768 * 256) {
            const int n = tid >> 8, k = tid & 255;
            Wqt[tid] = (_Float16)Wq[k * 768 + n];
        }
    } else {
        if (tid < 256 * 256) {
            const int n = tid >> 8, k = tid & 255;
            Wpt[tid] = (_Float16)Wp[k * 256 + n];
        }
    }
}

// ---------------------------------------------------------------------------
// MFMA fp16 GEMM, 128x128 tile, 4 waves (64x64 each), BK=64, K=256.
// MODE 0: qkv epilogue -> coalesced fp16 scatter via per-wave LDS transpose.
// MODE 1: proj epilogue (bias, fp32 out [M][NB]).
// Bijective XCD-chunked block swizzle (m204) — verified −5.5 us in r15.
// Linear LDS layout (T2 swizzle regressed on this 2-phase structure — r18).
// ---------------------------------------------------------------------------
template<int NB, int MODE>
__global__ __launch_bounds__(256)
void mfma_gemm_kernel(const _Float16* __restrict__ A,
                      const _Float16* __restrict__ Bt,
                      const float* __restrict__ bias,
                      _Float16* __restrict__ qo, _Float16* __restrict__ ko,
                      _Float16* __restrict__ vo, float* __restrict__ outf,
                      int M)
{
    __shared__ __align__(16) _Float16 Alds[128 * 64];
    __shared__ __align__(16) _Float16 Blds[128 * 64];

    const int tid  = threadIdx.x;
    const int wid  = tid >> 6;
    const int lane = tid & 63;

    // XCD-chunked bijective swizzle (m204): nwg not divisible by 8.
    const int nwg  = gridDim.x * gridDim.y;
    const int orig = blockIdx.x + gridDim.x * blockIdx.y;
    const int qq   = nwg >> 3;
    const int rr   = nwg & 7;
    const int xcd  = orig & 7;
    const int blk  = orig >> 3;
    const int wgid = (xcd < rr ? xcd * (qq + 1)
                               : rr * (qq + 1) + (xcd - rr) * qq) + blk;
    const int bn   = (wgid % gridDim.x) * 128;
    const int bm   = (wgid / gridDim.x) * 128;

    const int wr   = wid >> 1;
    const int wc   = wid & 1;

    f32x4 acc[4][4] = {};

    const int srow  = lane >> 3;
    const int sunit = (lane & 7) * 16;

    for (int k0 = 0; k0 < KDIM; k0 += 64) {
        #pragma unroll
        for (int i = 0; i < 4; ++i) {
            const int chunk = i * 4 + wid;
            const int row   = chunk * 8 + srow;
            int am = bm + row;
            am = (am < M) ? am : (M - 1);
            const char* asrc = (const char*)(A + (size_t)am * KDIM + k0) + sunit;
            __builtin_amdgcn_global_load_lds(
                (const __attribute__((address_space(1))) void*)asrc,
                (__attribute__((address_space(3))) void*)((char*)Alds + chunk * 1024),
                16, 0, 0);
            const char* bsrc = (const char*)(Bt + (size_t)(bn + row) * KDIM + k0) + sunit;
            __builtin_amdgcn_global_load_lds(
                (const __attribute__((address_space(1))) void*)bsrc,
                (__attribute__((address_space(3))) void*)((char*)Blds + chunk * 1024),
                16, 0, 0);
        }
        __syncthreads();
        #pragma unroll
        for (int kk = 0; kk < 64; kk += 32) {
            const int ko2 = kk + (lane >> 4) * 8;
            f16x8 af[4], bf[4];
            #pragma unroll
            for (int t = 0; t < 4; ++t) {
                af[t] = *(const f16x8*)&Alds[(wr * 64 + t * 16 + (lane & 15)) * 64 + ko2];
                bf[t] = *(const f16x8*)&Blds[(wc * 64 + t * 16 + (lane & 15)) * 64 + ko2];
            }
            #pragma unroll
            for (int fi = 0; fi < 4; ++fi)
                #pragma unroll
                for (int fj = 0; fj < 4; ++fj)
                    acc[fi][fj] = __builtin_amdgcn_mfma_f32_16x16x32_f16(
                        af[fi], bf[fj], acc[fi][fj], 0, 0, 0);
        }
        __syncthreads();
    }

    // epilogue — C/D layout: col = lane&15, row = (lane>>4)*4 + j
    const int lc  = lane & 15;
    const int lrb = (lane >> 4) * 4;
    if (MODE == 0) {
        const float scale = 0.17677669529663687f;
        _Float16* sw = Alds + wid * 640;   // 16 rows x 34 f16 (+pad), per-wave
        const int row = lane >> 2;          // 0..15
        const int seg = lane & 3;           // 0..3
        #pragma unroll
        for (int fi = 0; fi < 4; ++fi) {
            #pragma unroll
            for (int fp = 0; fp < 2; ++fp) {       // fj pair (2fp, 2fp+1)
                #pragma unroll
                for (int ff = 0; ff < 2; ++ff) {
                    const int fj = fp * 2 + ff;
                    const int c = bn + wc * 64 + fj * 16 + lc;
                    const float bv = bias[c];
                    const float scl = ((c >> 8) == 0) ? scale : 1.0f;
                    #pragma unroll
                    for (int j = 0; j < 4; ++j)
                        sw[(lrb + j) * 34 + ff * 16 + lc] =
                            (_Float16)((acc[fi][fj][j] + bv) * scl);
                }
                const int c0 = bn + wc * 64 + fp * 32;
                const int which = c0 >> 8;          // 0=q 1=k 2=v
                const int head  = (c0 >> 5) & 7;
                _Float16* dst = (which == 0) ? qo : (which == 1) ? ko : vo;
                const int m = bm + wr * 64 + fi * 16 + row;
                f16x8 vv = *(const f16x8*)&sw[row * 34 + seg * 8];
                if (m < M)
                    *(f16x8*)&dst[((size_t)head * M + m) * HD + seg * 8] = vv;
            }
        }
    } else {
        #pragma unroll
        for (int fj = 0; fj < 4; ++fj) {
            const int c = bn + wc * 64 + fj * 16 + lc;
            const float bv = bias[c];
            #pragma unroll
            for (int fi = 0; fi < 4; ++fi) {
                #pragma unroll
                for (int j = 0; j < 4; ++j) {
                    const int m = bm + wr * 64 + fi * 16 + lrb + j;
                    if (m < M)
                        outf[(size_t)m * NB + c] = acc[fi][fj][j] + bv;
                }
            }
        }
    }
}

// ---------------------------------------------------------------------------
// Attention (champion): one query per thread, (head, 8h x 32w tile), single
// time-shared 37.5 KB buffer, K/V via global_load_lds DMA, t-major
// conflict-free layout, no max-subtraction, q-hoist, softmax in V-DMA shadow,
// 4-chain ILP, per-head XCD-chunked block swizzle.
// ---------------------------------------------------------------------------
#define KROWS 14
#define KCOLS 38
#define KUNITS (KROWS * KCOLS * 4)   // 2128 x 16B
#define KUNITS_PAD 2304              // 9 x 256 (pad rows clamp-read, never used)

__device__ __forceinline__ void stage_dma(const uint4* __restrict__ src,
                                          uint4* __restrict__ dstlds,
                                          int n, int r0, int w0, int tid)
{
    const int wid  = tid >> 6;
    const int lane = tid & 63;
    #pragma unroll
    for (int it = 0; it < 9; ++it) {
        const int u0 = it * 256 + wid * 64;   // wave-uniform LDS base
        const int u  = u0 + lane;
        const int row = u / (KCOLS * 4);      // t-major: u = row*152 + t*38 + col
        const int rem = u - row * (KCOLS * 4);
        const int t   = rem / KCOLS;
        const int col = rem - t * KCOLS;
        int grow = r0 + row;
        if (grow > H_DIM - 1) grow = H_DIM - 1;
        int gcol = w0 - 3 + col;
        if (gcol < 0) gcol += W_DIM;
        else if (gcol >= W_DIM) gcol -= W_DIM;
        const size_t gidx = (((size_t)n * H_DIM + grow) * W_DIM + gcol) * 4 + t;
        __builtin_amdgcn_global_load_lds(
            (const __attribute__((address_space(1))) void*)(src + gidx),
            (__attribute__((address_space(3))) void*)(dstlds + u0), 16, 0, 0);
    }
}

__global__ __launch_bounds__(256)
void natten_attn_kernel(const _Float16* __restrict__ q,   // [8][M][32]
                        const uint4* __restrict__ kb,
                        const uint4* __restrict__ vb,
                        const float* __restrict__ rpb,    // [8][13][13]
                        _Float16* __restrict__ outh)      // [M][256]
{
    __shared__ uint4 kvs[KUNITS_PAD];
    __shared__ float rpbs[169];

    const int tid = threadIdx.x;
    const int n  = blockIdx.z;

    // per-head XCD-chunked bijective swizzle (m204): y-neighbors co-resident
    int w0, h0;
    {
        const int nwg   = gridDim.x * gridDim.y;          // 276
        const int local = blockIdx.x + gridDim.x * blockIdx.y;
        const int qq    = nwg >> 3;
        const int rr    = nwg & 7;
        const int xcd   = local & 7;
        const int blk   = local >> 3;
        const int lp    = (xcd < rr ? xcd * (qq + 1)
                                    : rr * (qq + 1) + (xcd - rr) * qq) + blk;
        w0 = (lp % gridDim.x) * 32;
        h0 = (lp / gridDim.x) * 8;
    }

    int r0 = h0 - 3;
    if (r0 < 0) r0 = 0;
    if (r0 > H_DIM - 7) r0 = H_DIM - 7;

    if (tid < 169) rpbs[tid] = rpb[n * 169 + tid];

    const int hl = tid >> 5;
    const int wl = tid & 31;
    const int h = h0 + hl;
    const int w = w0 + wl;
    const bool valid = (h < H_DIM) && (w < W_DIM);

    // ---- q global load issued BEFORE staging: completes under the DMA wait
    const int ha = (h < H_DIM) ? h : H_DIM - 1;
    const int wa = (w < W_DIM) ? w : W_DIM - 1;
    const uint4* qp = reinterpret_cast<const uint4*>(
        q + ((size_t)n * MPIX + (size_t)ha * W_DIM + wa) * HD);
    uint4 q0 = qp[0], q1 = qp[1], q2 = qp[2], q3 = qp[3];

    // ---- phase 1: stage K via DMA ----
    stage_dma(kb, kvs, n, r0, w0, tid);
    __syncthreads();

    h2 qh[16];
    qh[0]  = __builtin_bit_cast(h2, q0.x); qh[1]  = __builtin_bit_cast(h2, q0.y);
    qh[2]  = __builtin_bit_cast(h2, q0.z); qh[3]  = __builtin_bit_cast(h2, q0.w);
    qh[4]  = __builtin_bit_cast(h2, q1.x); qh[5]  = __builtin_bit_cast(h2, q1.y);
    qh[6]  = __builtin_bit_cast(h2, q1.z); qh[7]  = __builtin_bit_cast(h2, q1.w);
    qh[8]  = __builtin_bit_cast(h2, q2.x); qh[9]  = __builtin_bit_cast(h2, q2.y);
    qh[10] = __builtin_bit_cast(h2, q2.z); qh[11] = __builtin_bit_cast(h2, q2.w);
    qh[12] = __builtin_bit_cast(h2, q3.x); qh[13] = __builtin_bit_cast(h2, q3.y);
    qh[14] = __builtin_bit_cast(h2, q3.z); qh[15] = __builtin_bit_cast(h2, q3.w);

    float sc[49];
    int ri0 = 0;

    if (valid) {
        int sh = h - 3;
        if (sh < 0) sh = 0;
        if (sh > H_DIM - 7) sh = H_DIM - 7;
        ri0 = sh - r0;
        const int rh0 = sh - h + 6;

        #pragma unroll
        for (int oi = 0; oi < 7; ++oi) {
            const int rb = (ri0 + oi) * (KCOLS * 4);
            #pragma unroll
            for (int oj = 0; oj < 7; ++oj) {
                const int base = rb + wl + oj;
                float d0 = 0.f, d1 = 0.f, d2 = 0.f, d3 = 0.f;
                const uint4 ku0 = kvs[base];
                const uint4 ku1 = kvs[base + KCOLS];
                const uint4 ku2 = kvs[base + 2 * KCOLS];
                const uint4 ku3 = kvs[base + 3 * KCOLS];
#if HAS_FDOT2
                d0 = __builtin_amdgcn_fdot2(__builtin_bit_cast(h2, ku0.x), qh[0],  d0, false);
                d1 = __builtin_amdgcn_fdot2(__builtin_bit_cast(h2, ku1.x), qh[4],  d1, false);
                d2 = __builtin_amdgcn_fdot2(__builtin_bit_cast(h2, ku2.x), qh[8],  d2, false);
                d3 = __builtin_amdgcn_fdot2(__builtin_bit_cast(h2, ku3.x), qh[12], d3, false);
                d0 = __builtin_amdgcn_fdot2(__builtin_bit_cast(h2, ku0.y), qh[1],  d0, false);
                d1 = __builtin_amdgcn_fdot2(__builtin_bit_cast(h2, ku1.y), qh[5],  d1, false);
                d2 = __builtin_amdgcn_fdot2(__builtin_bit_cast(h2, ku2.y), qh[9],  d2, false);
                d3 = __builtin_amdgcn_fdot2(__builtin_bit_cast(h2, ku3.y), qh[13], d3, false);
                d0 = __builtin_amdgcn_fdot2(__builtin_bit_cast(h2, ku0.z), qh[2],  d0, false);
                d1 = __builtin_amdgcn_fdot2(__builtin_bit_cast(h2, ku1.z), qh[6],  d1, false);
                d2 = __builtin_amdgcn_fdot2(__builtin_bit_cast(h2, ku2.z), qh[10], d2, false);
                d3 = __builtin_amdgcn_fdot2(__builtin_bit_cast(h2, ku3.z), qh[14], d3, false);
                d0 = __builtin_amdgcn_fdot2(__builtin_bit_cast(h2, ku0.w), qh[3],  d0, false);
                d1 = __builtin_amdgcn_fdot2(__builtin_bit_cast(h2, ku1.w), qh[7],  d1, false);
                d2 = __builtin_amdgcn_fdot2(__builtin_bit_cast(h2, ku2.w), qh[11], d2, false);
                d3 = __builtin_amdgcn_fdot2(__builtin_bit_cast(h2, ku3.w), qh[15], d3, false);
#else
                {
                    h2 a, b;
                    a = __builtin_bit_cast(h2, ku0.x); b = qh[0];
                    d0 += (float)a.x * (float)b.x + (float)a.y * (float)b.y;
                    a = __builtin_bit_cast(h2, ku0.y); b = qh[1];
                    d0 += (float)a.x * (float)b.x + (float)a.y * (float)b.y;
                    a = __builtin_bit_cast(h2, ku0.z); b = qh[2];
                    d0 += (float)a.x * (float)b.x + (float)a.y * (float)b.y;
                    a = __builtin_bit_cast(h2, ku0.w); b = qh[3];
                    d0 += (float)a.x * (float)b.x + (float)a.y * (float)b.y;
                    a = __builtin_bit_cast(h2, ku1.x); b = qh[4];
                    d1 += (float)a.x * (float)b.x + (float)a.y * (float)b.y;
                    a = __builtin_bit_cast(h2, ku1.y); b = qh[5];
                    d1 += (float)a.x * (float)b.x + (float)a.y * (float)b.y;
                    a = __builtin_bit_cast(h2, ku1.z); b = qh[6];
                    d1 += (float)a.x * (float)b.x + (float)a.y * (float)b.y;
                    a = __builtin_bit_cast(h2, ku1.w); b = qh[7];
                    d1 += (float)a.x * (float)b.x + (float)a.y * (float)b.y;
                    a = __builtin_bit_cast(h2, ku2.x); b = qh[8];
                    d2 += (float)a.x * (float)b.x + (float)a.y * (float)b.y;
                    a = __builtin_bit_cast(h2, ku2.y); b = qh[9];
                    d2 += (float)a.x * (float)b.x + (float)a.y * (float)b.y;
                    a = __builtin_bit_cast(h2, ku2.z); b = qh[10];
                    d2 += (float)a.x * (float)b.x + (float)a.y * (float)b.y;
                    a = __builtin_bit_cast(h2, ku2.w); b = qh[11];
                    d2 += (float)a.x * (float)b.x + (float)a.y * (float)b.y;
                    a = __builtin_bit_cast(h2, ku3.x); b = qh[12];
                    d3 += (float)a.x * (float)b.x + (float)a.y * (float)b.y;
                    a = __builtin_bit_cast(h2, ku3.y); b = qh[13];
                    d3 += (float)a.x * (float)b.x + (float)a.y * (float)b.y;
                    a = __builtin_bit_cast(h2, ku3.z); b = qh[14];
                    d3 += (float)a.x * (float)b.x + (float)a.y * (float)b.y;
                    a = __builtin_bit_cast(h2, ku3.w); b = qh[15];
                    d3 += (float)a.x * (float)b.x + (float)a.y * (float)b.y;
                }
#endif
                sc[oi * 7 + oj] = ((d0 + d1) + (d2 + d3))
                                + rpbs[(rh0 + oi) * 13 + 3 + oj];
            }
        }
    }
    __syncthreads();

    // ---- phase 2: ISSUE V DMA, then do softmax in the DMA shadow ----
    stage_dma(vb, kvs, n, r0, w0, tid);

    float inv = 0.f;
    if (valid) {
        float ssum = 0.f;
        #pragma unroll
        for (int i = 0; i < 49; ++i) { sc[i] = __expf(sc[i]); ssum += sc[i]; }
        inv = 1.f / ssum;
    }
    __syncthreads();

    if (!valid) return;   // no barriers past this point

    float acc[32];
    #pragma unroll
    for (int t = 0; t < 32; ++t) acc[t] = 0.f;
    #pragma unroll
    for (int oi = 0; oi < 7; ++oi) {
        const int rb = (ri0 + oi) * (KCOLS * 4);
        #pragma unroll
        for (int oj = 0; oj < 7; ++oj) {
            const int base = rb + wl + oj;
            const float a = sc[oi * 7 + oj];
            #pragma unroll
            for (int t = 0; t < 4; ++t) {
                const uint4 vv = kvs[base + t * KCOLS];
                h2 v0 = __builtin_bit_cast(h2, vv.x);
                h2 v1 = __builtin_bit_cast(h2, vv.y);
                h2 v2 = __builtin_bit_cast(h2, vv.z);
                h2 v3 = __builtin_bit_cast(h2, vv.w);
                acc[t*8+0] += a * (float)v0.x; acc[t*8+1] += a * (float)v0.y;
                acc[t*8+2] += a * (float)v1.x; acc[t*8+3] += a * (float)v1.y;
                acc[t*8+4] += a * (float)v2.x; acc[t*8+5] += a * (float)v2.y;
                acc[t*8+6] += a * (float)v3.x; acc[t*8+7] += a * (float)v3.y;
            }
        }
    }

    uint4 o[4];
    #pragma unroll
    for (int t = 0; t < 4; ++t) {
        h2 p0 = { (_Float16)(acc[t*8+0] * inv), (_Float16)(acc[t*8+1] * inv) };
        h2 p1 = { (_Float16)(acc[t*8+2] * inv), (_Float16)(acc[t*8+3] * inv) };
        h2 p2 = { (_Float16)(acc[t*8+4] * inv), (_Float16)(acc[t*8+5] * inv) };
        h2 p3 = { (_Float16)(acc[t*8+6] * inv), (_Float16)(acc[t*8+7] * inv) };
        o[t].x = __builtin_bit_cast(unsigned, p0);
        o[t].y = __builtin_bit_cast(unsigned, p1);
        o[t].z = __builtin_bit_cast(unsigned, p2);
        o[t].w = __builtin_bit_cast(unsigned, p3);
    }
    uint4* op = reinterpret_cast<uint4*>(
        outh + (((size_t)h * W_DIM + w) * CH + n * HD));
    #pragma unroll
    for (int t = 0; t < 4; ++t) op[t] = o[t];
}

// ---------------------------------------------------------------------------
extern "C" void kernel_launch(void* const* d_in, const int* in_sizes, int n_in,
                              void* d_out, int out_size, void* d_ws, size_t ws_size,
                              hipStream_t stream)
{
    const float* x      = (const float*)d_in[0];
    const float* w_qkv  = (const float*)d_in[1];
    const float* b_qkv  = (const float*)d_in[2];
    const float* rpb    = (const float*)d_in[3];
    const float* w_proj = (const float*)d_in[4];
    const float* b_proj = (const float*)d_in[5];
    float* out = (float*)d_out;

    const int M = MPIX;
    const size_t nelem = (size_t)M * KDIM;

    _Float16* Xh  = (_Float16*)d_ws;
    _Float16* Wqt = Xh  + nelem;
    _Float16* Wpt = Wqt + 768 * 256;
    _Float16* qb  = Wpt + 256 * 256;
    _Float16* kb  = qb  + nelem;
    _Float16* vb  = kb  + nelem;
    _Float16* ah  = vb  + nelem;

    const size_t need = (5 * nelem + 768 * 256 + 256 * 256) * sizeof(_Float16);
    if (ws_size < need) return;

    dim3 blk(256);
    convert_kernel<<<dim3(8100, 3), blk, 0, stream>>>(x, w_qkv, w_proj, Xh, Wqt, Wpt);

    mfma_gemm_kernel<768, 0><<<dim3(6, 507), blk, 0, stream>>>(
        Xh, Wqt, b_qkv, qb, kb, vb, nullptr, M);

    natten_attn_kernel<<<dim3(12, 23, NHEAD), blk, 0, stream>>>(
        qb, (const uint4*)kb, (const uint4*)vb, rpb, ah);

    mfma_gemm_kernel<256, 1><<<dim3(2, 507), blk, 0, stream>>>(
        ah, Wpt, b_proj, nullptr, nullptr, nullptr, out, M);
}